// Round 2
// baseline (722.098 us; speedup 1.0000x reference)
//
#include <hip/hip_runtime.h>
#include <hip/hip_bf16.h>

#define DEV __device__ __forceinline__

using bf16x8 = __attribute__((ext_vector_type(8))) short;   // 8 bf16 in 4 VGPRs
using f32x4  = __attribute__((ext_vector_type(4))) float;

#define MFMA16(a, b, c) __builtin_amdgcn_mfma_f32_16x16x32_bf16((a), (b), (c), 0, 0, 0)

// async global->LDS, 16 bytes per lane. LDS dst must be wave-uniform base + lane*16.
#define GLOAD_LDS16(gp, lp)                                                        \
  __builtin_amdgcn_global_load_lds(                                               \
      (__attribute__((address_space(1))) unsigned int*)(gp),                      \
      (__attribute__((address_space(3))) unsigned int*)(lp), 16, 0, 0)

DEV float b2f(unsigned short u) {
  union { float f; unsigned u; } x; x.u = ((unsigned)u) << 16; return x.f;
}
DEV unsigned short f2b(float f) {   // round-to-nearest-even bf16
  union { float f; unsigned u; } x; x.f = f;
  unsigned r = x.u + 0x7FFFu + ((x.u >> 16) & 1u);
  return (unsigned short)(r >> 16);
}

// ---------------------------------------------------------------------------
// Dtype detector: if hidden_states is really fp32, its low u16 halves contain
// random mantissa bits -> ~1/256 decode as bf16 NaN/Inf (exp==0xFF). True bf16
// gaussian data has zero such patterns. One block scans 128K u16s.
// ---------------------------------------------------------------------------
__global__ __launch_bounds__(256) void detect_kernel(
    const unsigned short* __restrict__ hs, int* __restrict__ flag) {
  __shared__ int red[4];
  const int t = threadIdx.x;
  int cnt = 0;
  for (int i = t; i < 131072; i += 256) {
    unsigned short u = hs[i];
    if (((u >> 7) & 0xFF) == 0xFF) cnt++;
  }
#pragma unroll
  for (int off = 32; off >= 1; off >>= 1) cnt += __shfl_xor(cnt, off, 64);
  if ((t & 63) == 0) red[t >> 6] = cnt;
  __syncthreads();
  if (t == 0) flag[0] = (red[0] + red[1] + red[2] + red[3] >= 16) ? 1 : 0;
}

// Convert one tensor (n % 4 == 0) to bf16, honoring the fp32 flag.
__global__ __launch_bounds__(256) void convert_kernel(
    const void* __restrict__ src, unsigned short* __restrict__ dst, int n,
    const int* __restrict__ flag) {
  const int i = (blockIdx.x * 256 + threadIdx.x) * 4;
  if (i >= n) return;
  ushort4 o;
  if (*flag) {
    float4 f = ((const float4*)src)[i >> 2];
    o.x = f2b(f.x); o.y = f2b(f.y); o.z = f2b(f.z); o.w = f2b(f.w);
  } else {
    o = ((const ushort4*)src)[i >> 2];
  }
  ((ushort4*)dst)[i >> 2] = o;
}

// Convert the 5 [1024,1024] weights in one launch (blockIdx.y selects tensor).
__global__ __launch_bounds__(256) void convert_w_kernel(
    const void* __restrict__ s0, const void* __restrict__ s1,
    const void* __restrict__ s2, const void* __restrict__ s3,
    const void* __restrict__ s4, unsigned short* __restrict__ dst,
    const int* __restrict__ flag) {
  const void* srcs[5] = {s0, s1, s2, s3, s4};
  const void* src = srcs[blockIdx.y];
  unsigned short* d = dst + (long)blockIdx.y * 1048576;
  const int i = (blockIdx.x * 256 + threadIdx.x) * 4;
  ushort4 o;
  if (*flag) {
    float4 f = ((const float4*)src)[i >> 2];
    o.x = f2b(f.x); o.y = f2b(f.y); o.z = f2b(f.z); o.w = f2b(f.w);
  } else {
    o = ((const ushort4*)src)[i >> 2];
  }
  ((ushort4*)d)[i >> 2] = o;
}

// Convert the 7 length-1024 vectors (blockIdx.x selects tensor).
__global__ __launch_bounds__(256) void convert_vec_kernel(
    const void* __restrict__ s0, const void* __restrict__ s1,
    const void* __restrict__ s2, const void* __restrict__ s3,
    const void* __restrict__ s4, const void* __restrict__ s5,
    const void* __restrict__ s6, unsigned short* __restrict__ dst,
    const int* __restrict__ flag) {
  const void* srcs[7] = {s0, s1, s2, s3, s4, s5, s6};
  const void* src = srcs[blockIdx.x];
  unsigned short* d = dst + blockIdx.x * 1024;
  const int i = threadIdx.x * 4;
  ushort4 o;
  if (*flag) {
    float4 f = ((const float4*)src)[i >> 2];
    o.x = f2b(f.x); o.y = f2b(f.y); o.z = f2b(f.z); o.w = f2b(f.w);
  } else {
    o = ((const ushort4*)src)[i >> 2];
  }
  ((ushort4*)d)[i >> 2] = o;
}

// ---------------------------------------------------------------------------
// GEMM: C[m,n] = scale * sum_k A[m,k]*B[n,k] + bias[n]  (B stored row-major [N,K])
// Tile 128x128, BK=32, 256 threads = 4 waves in 2x2, each wave 64x64 (4x4 MFMA tiles).
// ---------------------------------------------------------------------------
template <int RELU, int OUTBF16, int BIAS>
__global__ __launch_bounds__(256, 2) void gemm_bt_kernel(
    const unsigned short* __restrict__ A, const unsigned short* __restrict__ B,
    const unsigned short* __restrict__ bias, void* __restrict__ Cv,
    int M, int N, int K, long sA_, long sB_, long sC_, float scale) {
  __shared__ unsigned short sA[128 * 32];
  __shared__ unsigned short sB[128 * 32];
  const int t = threadIdx.x;
  const int wave = t >> 6, lane = t & 63;
  const int quad = lane >> 4, col = lane & 15;
  const int wm = wave >> 1, wn = wave & 1;
  const long zb = blockIdx.z;
  const unsigned short* Ab = A + zb * sA_ + (long)blockIdx.x * 128 * K;
  const unsigned short* Bb = B + zb * sB_ + (long)blockIdx.y * 128 * K;
  const int r0 = t >> 2;          // 0..63
  const int c0 = (t & 3) * 8;     // 0,8,16,24

  f32x4 zz = {0.f, 0.f, 0.f, 0.f};
  f32x4 acc[4][4];
#pragma unroll
  for (int i = 0; i < 4; i++)
#pragma unroll
    for (int j = 0; j < 4; j++) acc[i][j] = zz;

  for (int k0 = 0; k0 < K; k0 += 32) {
    __syncthreads();
    GLOAD_LDS16(Ab + (long)r0 * K + k0 + c0,        &sA[t * 8]);
    GLOAD_LDS16(Ab + (long)(64 + r0) * K + k0 + c0, &sA[2048 + t * 8]);
    GLOAD_LDS16(Bb + (long)r0 * K + k0 + c0,        &sB[t * 8]);
    GLOAD_LDS16(Bb + (long)(64 + r0) * K + k0 + c0, &sB[2048 + t * 8]);
    __syncthreads();
    bf16x8 af[4], bfr[4];
#pragma unroll
    for (int mi = 0; mi < 4; mi++)
      af[mi] = *(const bf16x8*)&sA[(wm * 64 + mi * 16 + col) * 32 + quad * 8];
#pragma unroll
    for (int ni = 0; ni < 4; ni++)
      bfr[ni] = *(const bf16x8*)&sB[(wn * 64 + ni * 16 + col) * 32 + quad * 8];
#pragma unroll
    for (int mi = 0; mi < 4; mi++)
#pragma unroll
      for (int ni = 0; ni < 4; ni++)
        acc[mi][ni] = MFMA16(af[mi], bfr[ni], acc[mi][ni]);
  }

  const int Rm = blockIdx.x * 128 + wm * 64;
  const int Cn = blockIdx.y * 128 + wn * 64;
  float bs[4];
#pragma unroll
  for (int ni = 0; ni < 4; ni++)
    bs[ni] = BIAS ? b2f(bias[Cn + ni * 16 + col]) : 0.f;
#pragma unroll
  for (int mi = 0; mi < 4; mi++)
#pragma unroll
    for (int ni = 0; ni < 4; ni++)
#pragma unroll
      for (int r = 0; r < 4; r++) {
        int rr = Rm + mi * 16 + quad * 4 + r;
        int cc = Cn + ni * 16 + col;
        float v = acc[mi][ni][r] * scale + bs[ni];
        if (RELU) v = fmaxf(v, 0.f);
        if (OUTBF16)
          ((unsigned short*)Cv)[zb * sC_ + (long)rr * N + cc] = f2b(v);
        else
          ((float*)Cv)[zb * sC_ + (long)rr * N + cc] = v;
      }
}

// ---------------------------------------------------------------------------
// Row softmax: S fp32 [rows,1024] -> P bf16. One block (256 thr) per row.
// ---------------------------------------------------------------------------
__global__ __launch_bounds__(256) void softmax_kernel(
    const float* __restrict__ S, unsigned short* __restrict__ P) {
  __shared__ float red[8];
  const long row = blockIdx.x;
  const int t = threadIdx.x;
  const float4 v4 = ((const float4*)(S + row * 1024))[t];
  float x[4] = {v4.x, v4.y, v4.z, v4.w};
  float m = fmaxf(fmaxf(x[0], x[1]), fmaxf(x[2], x[3]));
#pragma unroll
  for (int off = 32; off >= 1; off >>= 1) m = fmaxf(m, __shfl_xor(m, off, 64));
  if ((t & 63) == 0) red[t >> 6] = m;
  __syncthreads();
  m = fmaxf(fmaxf(red[0], red[1]), fmaxf(red[2], red[3]));
  float e[4], s = 0.f;
#pragma unroll
  for (int i = 0; i < 4; i++) { e[i] = __expf(x[i] - m); s += e[i]; }
#pragma unroll
  for (int off = 32; off >= 1; off >>= 1) s += __shfl_xor(s, off, 64);
  __syncthreads();
  if ((t & 63) == 0) red[4 + (t >> 6)] = s;
  __syncthreads();
  s = red[4] + red[5] + red[6] + red[7];
  float inv = 1.f / s;
  ushort4 o;
  o.x = f2b(e[0] * inv); o.y = f2b(e[1] * inv);
  o.z = f2b(e[2] * inv); o.w = f2b(e[3] * inv);
  ((ushort4*)(P + row * 1024))[t] = o;
}

// ---------------------------------------------------------------------------
// LayerNorm over last dim 1024 (bf16 in/out). One block per row.
// ---------------------------------------------------------------------------
DEV float block_sum(float v, float* red, int t) {
#pragma unroll
  for (int off = 32; off >= 1; off >>= 1) v += __shfl_xor(v, off, 64);
  __syncthreads();
  if ((t & 63) == 0) red[t >> 6] = v;
  __syncthreads();
  return red[0] + red[1] + red[2] + red[3];
}

__global__ __launch_bounds__(256) void layernorm_kernel(
    const unsigned short* __restrict__ X, const unsigned short* __restrict__ G,
    const unsigned short* __restrict__ Bt, unsigned short* __restrict__ Y) {
  __shared__ float red[4];
  const long row = blockIdx.x;
  const int t = threadIdx.x;
  ushort4 u = ((const ushort4*)(X + row * 1024))[t];
  float x[4] = {b2f(u.x), b2f(u.y), b2f(u.z), b2f(u.w)};
  float s = x[0] + x[1] + x[2] + x[3];
  float mean = block_sum(s, red, t) * (1.f / 1024.f);
  float d0 = x[0] - mean, d1 = x[1] - mean, d2 = x[2] - mean, d3 = x[3] - mean;
  float vs = d0 * d0 + d1 * d1 + d2 * d2 + d3 * d3;
  float var = block_sum(vs, red, t) * (1.f / 1024.f);
  float rs = rsqrtf(var + 1e-5f);
  ushort4 gu = ((const ushort4*)G)[t];
  ushort4 bu = ((const ushort4*)Bt)[t];
  ushort4 o;
  o.x = f2b(d0 * rs * b2f(gu.x) + b2f(bu.x));
  o.y = f2b(d1 * rs * b2f(gu.y) + b2f(bu.y));
  o.z = f2b(d2 * rs * b2f(gu.z) + b2f(bu.z));
  o.w = f2b(d3 * rs * b2f(gu.w) + b2f(bu.w));
  ((ushort4*)(Y + row * 1024))[t] = o;
}

// ---------------------------------------------------------------------------
// Transpose per batch: V[b][sk][d] -> VT[b][d][sk]  (bf16, 1024x1024 per batch)
// ---------------------------------------------------------------------------
__global__ __launch_bounds__(256) void transpose_kernel(
    const unsigned short* __restrict__ V, unsigned short* __restrict__ VT) {
  __shared__ unsigned short tile[32][33];
  const int b = blockIdx.z;
  const int d0 = blockIdx.x * 32, sk0 = blockIdx.y * 32;
  const int tx = threadIdx.x & 31, ty = threadIdx.x >> 5;  // ty 0..7
#pragma unroll
  for (int i = 0; i < 32; i += 8)
    tile[ty + i][tx] = V[((long)(b * 1024 + sk0 + ty + i)) * 1024 + d0 + tx];
  __syncthreads();
#pragma unroll
  for (int i = 0; i < 32; i += 8)
    VT[((long)(b * 1024 + d0 + ty + i)) * 1024 + sk0 + tx] = tile[tx][ty + i];
}

// ---------------------------------------------------------------------------
// Flash MHA: H=16 heads of DH=64. Q,K: [B,1024,1024] bf16 (new_q/new_k),
// VT: [B][d][sk] bf16. Out fp32 or bf16 per flag. Block = 4 waves, each wave
// owns 16 q-rows with private online-softmax state; kv-tiles of 32.
// ---------------------------------------------------------------------------
__global__ __launch_bounds__(256, 2) void flash_mha_kernel(
    const unsigned short* __restrict__ Q, const unsigned short* __restrict__ K,
    const unsigned short* __restrict__ VT, void* __restrict__ O,
    const int* __restrict__ flag) {
  __shared__ unsigned short pbuf[4][16 * 32];
  const int t = threadIdx.x;
  const int wave = t >> 6, lane = t & 63;
  const int quad = lane >> 4, col = lane & 15;
  const int b = blockIdx.z, h = blockIdx.y;
  const int q0 = blockIdx.x * 64 + wave * 16;

  const unsigned short* qp =
      Q + ((long)(b * 1024 + q0 + col)) * 1024 + h * 64 + quad * 8;
  bf16x8 aq0 = *(const bf16x8*)(qp);
  bf16x8 aq1 = *(const bf16x8*)(qp + 32);

  f32x4 zz = {0.f, 0.f, 0.f, 0.f};
  f32x4 o0 = zz, o1 = zz, o2 = zz, o3 = zz;
  float m_i[4] = {-1e30f, -1e30f, -1e30f, -1e30f};
  float l_i[4] = {0.f, 0.f, 0.f, 0.f};

  const unsigned short* kb0 = K + ((long)b * 1024) * 1024 + h * 64 + quad * 8;
  const unsigned short* vb =
      VT + ((long)(b * 1024 + h * 64)) * 1024 + quad * 8;
  unsigned short* pw = &pbuf[wave][0];

  for (int kv0 = 0; kv0 < 1024; kv0 += 32) {
    const unsigned short* kb = kb0 + (long)(kv0 + col) * 1024;
    bf16x8 k00 = *(const bf16x8*)(kb);
    bf16x8 k01 = *(const bf16x8*)(kb + 32);
    bf16x8 k10 = *(const bf16x8*)(kb + 16 * 1024);
    bf16x8 k11 = *(const bf16x8*)(kb + 16 * 1024 + 32);
    f32x4 s0 = zz, s1 = zz;
    s0 = MFMA16(aq0, k00, s0); s0 = MFMA16(aq1, k01, s0);
    s1 = MFMA16(aq0, k10, s1); s1 = MFMA16(aq1, k11, s1);
    float al[4];
#pragma unroll
    for (int r = 0; r < 4; r++) {
      float a = s0[r] * 0.125f, c = s1[r] * 0.125f;
      float mr = fmaxf(a, c);
#pragma unroll
      for (int off = 1; off < 16; off <<= 1) mr = fmaxf(mr, __shfl_xor(mr, off, 16));
      float nm = fmaxf(m_i[r], mr);
      float alpha = __expf(m_i[r] - nm);
      float p0 = __expf(a - nm), p1 = __expf(c - nm);
      float rs = p0 + p1;
#pragma unroll
      for (int off = 1; off < 16; off <<= 1) rs += __shfl_xor(rs, off, 16);
      l_i[r] = l_i[r] * alpha + rs;
      m_i[r] = nm;
      al[r] = alpha;
      pw[(quad * 4 + r) * 32 + col] = f2b(p0);
      pw[(quad * 4 + r) * 32 + 16 + col] = f2b(p1);
    }
#pragma unroll
    for (int r = 0; r < 4; r++) {
      o0[r] *= al[r]; o1[r] *= al[r]; o2[r] *= al[r]; o3[r] *= al[r];
    }
    __asm__ __volatile__("s_waitcnt lgkmcnt(0)" ::: "memory");
    bf16x8 ap = *(const bf16x8*)&pw[col * 32 + quad * 8];
    const unsigned short* vp = vb + kv0;
    bf16x8 v0 = *(const bf16x8*)(vp + (long)(col) * 1024);
    bf16x8 v1 = *(const bf16x8*)(vp + (long)(16 + col) * 1024);
    bf16x8 v2 = *(const bf16x8*)(vp + (long)(32 + col) * 1024);
    bf16x8 v3 = *(const bf16x8*)(vp + (long)(48 + col) * 1024);
    o0 = MFMA16(ap, v0, o0); o1 = MFMA16(ap, v1, o1);
    o2 = MFMA16(ap, v2, o2); o3 = MFMA16(ap, v3, o3);
  }
  const int f32o = *flag;
  const long base = ((long)(b * 1024 + q0 + quad * 4)) * 1024 + h * 64 + col;
#pragma unroll
  for (int r = 0; r < 4; r++) {
    float inv = 1.f / l_i[r];
    float x0 = o0[r] * inv, x1 = o1[r] * inv, x2 = o2[r] * inv, x3 = o3[r] * inv;
    long idx = base + (long)r * 1024;
    if (f32o) {
      float* Of = (float*)O;
      Of[idx] = x0; Of[idx + 16] = x1; Of[idx + 32] = x2; Of[idx + 48] = x3;
    } else {
      unsigned short* Ou = (unsigned short*)O;
      Ou[idx] = f2b(x0); Ou[idx + 16] = f2b(x1);
      Ou[idx + 32] = f2b(x2); Ou[idx + 48] = f2b(x3);
    }
  }
}

// ---------------------------------------------------------------------------
extern "C" void kernel_launch(void* const* d_in, const int* in_sizes, int n_in,
                              void* d_out, int out_size, void* d_ws,
                              size_t ws_size, hipStream_t stream) {
  (void)in_sizes; (void)n_in; (void)out_size; (void)ws_size;
  const void* hs   = d_in[0];
  const void* ctx  = d_in[1];
  const void* Wq   = d_in[2];
  const void* bq   = d_in[3];
  const void* Wk   = d_in[4];
  const void* bk   = d_in[5];
  const void* Wv   = d_in[6];
  const void* bv   = d_in[7];
  const void* Wobs = d_in[8];
  const void* bobs = d_in[9];
  const void* Wmat = d_in[10];
  const void* bmat = d_in[11];
  const void* lng  = d_in[12];
  const void* lnb  = d_in[13];

  const long E = 8LL * 1024 * 1024;   // elems per [B,1024,1024] tensor
  const long W1 = 1024L * 1024L;      // elems per weight
  unsigned short* base = (unsigned short*)d_ws;
  // Aliased layout, 140 MB total:
  unsigned short* hsb   = base;                 // [later: probs]
  unsigned short* ctxb  = base + E;             // [later: gctx]
  unsigned short* Wb    = base + 2 * E;         // 5 x 1M
  unsigned short* Wqb   = Wb;
  unsigned short* Wkb   = Wb + W1;
  unsigned short* Wvb   = Wb + 2 * W1;
  unsigned short* Wobsb = Wb + 3 * W1;
  unsigned short* Wmatb = Wb + 4 * W1;
  unsigned short* vecs  = base + 2 * E + 5 * W1;  // 7 x 1024 + flag
  unsigned short* bqb   = vecs;
  unsigned short* bkb   = vecs + 1024;
  unsigned short* bvb   = vecs + 2048;
  unsigned short* bobsb = vecs + 3072;
  unsigned short* bmatb = vecs + 4096;
  unsigned short* lngb  = vecs + 5120;
  unsigned short* lnbb  = vecs + 6144;
  int* flag = (int*)(vecs + 32768);
  unsigned short* q     = vecs + W1;            // [later: newk]
  unsigned short* k     = q + E;
  unsigned short* v     = k + E;                // [later: nk]
  unsigned short* vT    = v + E;
  float* scores = (float*)(vT + E);             // 32 MB fp32
  unsigned short* nq    = (unsigned short*)scores;      // alias scores[0:16MB]
  unsigned short* newq  = ((unsigned short*)scores) + E; // alias scores[16:32MB]
  unsigned short* probs = hsb;
  unsigned short* gctx  = ctxb;
  unsigned short* nk    = v;
  unsigned short* newk  = q;

  dim3 blk(256);
  const long S1 = 1024L * 1024L;

  // --- dtype detect + convert everything to bf16 internal copies ---
  detect_kernel<<<dim3(1), blk, 0, stream>>>((const unsigned short*)hs, flag);
  convert_kernel<<<dim3(8192), blk, 0, stream>>>(hs, hsb, (int)E, flag);
  convert_kernel<<<dim3(8192), blk, 0, stream>>>(ctx, ctxb, (int)E, flag);
  convert_w_kernel<<<dim3(1024, 5), blk, 0, stream>>>(Wq, Wk, Wv, Wobs, Wmat, Wb, flag);
  convert_vec_kernel<<<dim3(7), blk, 0, stream>>>(bq, bk, bv, bobs, bmat, lng, lnb,
                                                  vecs, flag);

  // q/k/v projections: [8192,1024] = [8192,1024] @ W^T + b
  gemm_bt_kernel<0, 1, 1><<<dim3(64, 8, 1), blk, 0, stream>>>(
      hsb, Wqb, bqb, q, 8192, 1024, 1024, 0, 0, 0, 1.f);
  gemm_bt_kernel<0, 1, 1><<<dim3(64, 8, 1), blk, 0, stream>>>(
      ctxb, Wkb, bkb, k, 8192, 1024, 1024, 0, 0, 0, 1.f);
  gemm_bt_kernel<0, 1, 1><<<dim3(64, 8, 1), blk, 0, stream>>>(
      ctxb, Wvb, bvb, v, 8192, 1024, 1024, 0, 0, 0, 1.f);
  // vT[b][d][sk]
  transpose_kernel<<<dim3(32, 32, 8), blk, 0, stream>>>(v, vT);
  // scores[b] = q[b] @ k[b]^T / 32  (fp32)
  gemm_bt_kernel<0, 0, 0><<<dim3(8, 8, 8), blk, 0, stream>>>(
      q, k, nullptr, scores, 1024, 1024, 1024, S1, S1, S1, 0.03125f);
  softmax_kernel<<<dim3(8192), blk, 0, stream>>>(scores, probs);
  // gctx[b] = probs[b] @ v[b]  (as probs @ vT^T)
  gemm_bt_kernel<0, 1, 0><<<dim3(8, 8, 8), blk, 0, stream>>>(
      probs, vT, nullptr, gctx, 1024, 1024, 1024, S1, S1, S1, 1.f);
  // nq = relu(gctx @ Wobs^T + bobs); nk = relu(k @ Wmat^T + bmat)
  gemm_bt_kernel<1, 1, 1><<<dim3(64, 8, 1), blk, 0, stream>>>(
      gctx, Wobsb, bobsb, nq, 8192, 1024, 1024, 0, 0, 0, 1.f);
  gemm_bt_kernel<1, 1, 1><<<dim3(64, 8, 1), blk, 0, stream>>>(
      k, Wmatb, bmatb, nk, 8192, 1024, 1024, 0, 0, 0, 1.f);
  // LayerNorms
  layernorm_kernel<<<dim3(8192), blk, 0, stream>>>(nq, lngb, lnbb, newq);
  layernorm_kernel<<<dim3(8192), blk, 0, stream>>>(nk, lngb, lnbb, newk);
  // MHA
  flash_mha_kernel<<<dim3(16, 16, 8), blk, 0, stream>>>(
      newq, newk, vT, d_out, flag);
}

// Round 3
// 550.688 us; speedup vs baseline: 1.3113x; 1.3113x over previous
//
#include <hip/hip_runtime.h>
#include <hip/hip_bf16.h>

#define DEV __device__ __forceinline__

using bf16x8 = __attribute__((ext_vector_type(8))) short;   // 8 bf16 in 4 VGPRs
using f32x4  = __attribute__((ext_vector_type(4))) float;

#define MFMA16(a, b, c) __builtin_amdgcn_mfma_f32_16x16x32_bf16((a), (b), (c), 0, 0, 0)

// async global->LDS, 16 bytes per lane. LDS dst must be wave-uniform base + lane*16.
#define GLOAD_LDS16(gp, lp)                                                        \
  __builtin_amdgcn_global_load_lds(                                               \
      (__attribute__((address_space(1))) unsigned int*)(gp),                      \
      (__attribute__((address_space(3))) unsigned int*)(lp), 16, 0, 0)

DEV float b2f(unsigned short u) {
  union { float f; unsigned u; } x; x.u = ((unsigned)u) << 16; return x.f;
}
DEV unsigned short f2b(float f) {   // round-to-nearest-even bf16
  union { float f; unsigned u; } x; x.f = f;
  unsigned r = x.u + 0x7FFFu + ((x.u >> 16) & 1u);
  return (unsigned short)(r >> 16);
}
DEV unsigned short f2b_trunc(float f) {  // truncate: bias cancels (l from same P)
  union { float f; unsigned u; } x; x.f = f;
  return (unsigned short)(x.u >> 16);
}

// ---------------------------------------------------------------------------
// Dtype detector: fp32 data read as u16 halves shows bf16 NaN/Inf exponent
// patterns (~1/256); true bf16 gaussian data shows none.
// ---------------------------------------------------------------------------
__global__ __launch_bounds__(256) void detect_kernel(
    const unsigned short* __restrict__ hs, int* __restrict__ flag) {
  __shared__ int red[4];
  const int t = threadIdx.x;
  int cnt = 0;
  for (int i = t; i < 131072; i += 256) {
    unsigned short u = hs[i];
    if (((u >> 7) & 0xFF) == 0xFF) cnt++;
  }
#pragma unroll
  for (int off = 32; off >= 1; off >>= 1) cnt += __shfl_xor(cnt, off, 64);
  if ((t & 63) == 0) red[t >> 6] = cnt;
  __syncthreads();
  if (t == 0) flag[0] = (red[0] + red[1] + red[2] + red[3] >= 16) ? 1 : 0;
}

__global__ __launch_bounds__(256) void convert_kernel(
    const void* __restrict__ src, unsigned short* __restrict__ dst, int n,
    const int* __restrict__ flag) {
  const int i = (blockIdx.x * 256 + threadIdx.x) * 4;
  if (i >= n) return;
  ushort4 o;
  if (*flag) {
    float4 f = ((const float4*)src)[i >> 2];
    o.x = f2b(f.x); o.y = f2b(f.y); o.z = f2b(f.z); o.w = f2b(f.w);
  } else {
    o = ((const ushort4*)src)[i >> 2];
  }
  ((ushort4*)dst)[i >> 2] = o;
}

__global__ __launch_bounds__(256) void convert_w_kernel(
    const void* __restrict__ s0, const void* __restrict__ s1,
    const void* __restrict__ s2, const void* __restrict__ s3,
    const void* __restrict__ s4, unsigned short* __restrict__ dst,
    const int* __restrict__ flag) {
  const void* srcs[5] = {s0, s1, s2, s3, s4};
  const void* src = srcs[blockIdx.y];
  unsigned short* d = dst + (long)blockIdx.y * 1048576;
  const int i = (blockIdx.x * 256 + threadIdx.x) * 4;
  ushort4 o;
  if (*flag) {
    float4 f = ((const float4*)src)[i >> 2];
    o.x = f2b(f.x); o.y = f2b(f.y); o.z = f2b(f.z); o.w = f2b(f.w);
  } else {
    o = ((const ushort4*)src)[i >> 2];
  }
  ((ushort4*)d)[i >> 2] = o;
}

__global__ __launch_bounds__(256) void convert_vec_kernel(
    const void* __restrict__ s0, const void* __restrict__ s1,
    const void* __restrict__ s2, const void* __restrict__ s3,
    const void* __restrict__ s4, const void* __restrict__ s5,
    const void* __restrict__ s6, unsigned short* __restrict__ dst,
    const int* __restrict__ flag) {
  const void* srcs[7] = {s0, s1, s2, s3, s4, s5, s6};
  const void* src = srcs[blockIdx.x];
  unsigned short* d = dst + blockIdx.x * 1024;
  const int i = threadIdx.x * 4;
  ushort4 o;
  if (*flag) {
    float4 f = ((const float4*)src)[i >> 2];
    o.x = f2b(f.x); o.y = f2b(f.y); o.z = f2b(f.z); o.w = f2b(f.w);
  } else {
    o = ((const ushort4*)src)[i >> 2];
  }
  ((ushort4*)d)[i >> 2] = o;
}

// ---------------------------------------------------------------------------
// GEMM: C[m,n] = scale * sum_k A[m,k]*B[n,k] + bias[n]  (B row-major [N,K])
// Tile 128x128, BK=32, 4 waves 2x2, each wave 64x64 (4x4 MFMA tiles).
// ---------------------------------------------------------------------------
template <int RELU, int OUTBF16, int BIAS>
__global__ __launch_bounds__(256, 2) void gemm_bt_kernel(
    const unsigned short* __restrict__ A, const unsigned short* __restrict__ B,
    const unsigned short* __restrict__ bias, void* __restrict__ Cv,
    int M, int N, int K, long sA_, long sB_, long sC_, float scale) {
  __shared__ unsigned short sA[128 * 32];
  __shared__ unsigned short sB[128 * 32];
  const int t = threadIdx.x;
  const int wave = t >> 6, lane = t & 63;
  const int quad = lane >> 4, col = lane & 15;
  const int wm = wave >> 1, wn = wave & 1;
  const long zb = blockIdx.z;
  const unsigned short* Ab = A + zb * sA_ + (long)blockIdx.x * 128 * K;
  const unsigned short* Bb = B + zb * sB_ + (long)blockIdx.y * 128 * K;
  const int r0 = t >> 2;
  const int c0 = (t & 3) * 8;

  f32x4 zz = {0.f, 0.f, 0.f, 0.f};
  f32x4 acc[4][4];
#pragma unroll
  for (int i = 0; i < 4; i++)
#pragma unroll
    for (int j = 0; j < 4; j++) acc[i][j] = zz;

  for (int k0 = 0; k0 < K; k0 += 32) {
    __syncthreads();
    GLOAD_LDS16(Ab + (long)r0 * K + k0 + c0,        &sA[t * 8]);
    GLOAD_LDS16(Ab + (long)(64 + r0) * K + k0 + c0, &sA[2048 + t * 8]);
    GLOAD_LDS16(Bb + (long)r0 * K + k0 + c0,        &sB[t * 8]);
    GLOAD_LDS16(Bb + (long)(64 + r0) * K + k0 + c0, &sB[2048 + t * 8]);
    __syncthreads();
    bf16x8 af[4], bfr[4];
#pragma unroll
    for (int mi = 0; mi < 4; mi++)
      af[mi] = *(const bf16x8*)&sA[(wm * 64 + mi * 16 + col) * 32 + quad * 8];
#pragma unroll
    for (int ni = 0; ni < 4; ni++)
      bfr[ni] = *(const bf16x8*)&sB[(wn * 64 + ni * 16 + col) * 32 + quad * 8];
#pragma unroll
    for (int mi = 0; mi < 4; mi++)
#pragma unroll
      for (int ni = 0; ni < 4; ni++)
        acc[mi][ni] = MFMA16(af[mi], bfr[ni], acc[mi][ni]);
  }

  const int Rm = blockIdx.x * 128 + wm * 64;
  const int Cn = blockIdx.y * 128 + wn * 64;
  float bs[4];
#pragma unroll
  for (int ni = 0; ni < 4; ni++)
    bs[ni] = BIAS ? b2f(bias[Cn + ni * 16 + col]) : 0.f;
#pragma unroll
  for (int mi = 0; mi < 4; mi++)
#pragma unroll
    for (int ni = 0; ni < 4; ni++)
#pragma unroll
      for (int r = 0; r < 4; r++) {
        int rr = Rm + mi * 16 + quad * 4 + r;
        int cc = Cn + ni * 16 + col;
        float v = acc[mi][ni][r] * scale + bs[ni];
        if (RELU) v = fmaxf(v, 0.f);
        if (OUTBF16)
          ((unsigned short*)Cv)[zb * sC_ + (long)rr * N + cc] = f2b(v);
        else
          ((float*)Cv)[zb * sC_ + (long)rr * N + cc] = v;
      }
}

// ---------------------------------------------------------------------------
// Row softmax: S fp32 [rows,1024] -> P bf16. One block per row.
// ---------------------------------------------------------------------------
__global__ __launch_bounds__(256) void softmax_kernel(
    const float* __restrict__ S, unsigned short* __restrict__ P) {
  __shared__ float red[8];
  const long row = blockIdx.x;
  const int t = threadIdx.x;
  const float4 v4 = ((const float4*)(S + row * 1024))[t];
  float x[4] = {v4.x, v4.y, v4.z, v4.w};
  float m = fmaxf(fmaxf(x[0], x[1]), fmaxf(x[2], x[3]));
#pragma unroll
  for (int off = 32; off >= 1; off >>= 1) m = fmaxf(m, __shfl_xor(m, off, 64));
  if ((t & 63) == 0) red[t >> 6] = m;
  __syncthreads();
  m = fmaxf(fmaxf(red[0], red[1]), fmaxf(red[2], red[3]));
  float e[4], s = 0.f;
#pragma unroll
  for (int i = 0; i < 4; i++) { e[i] = __expf(x[i] - m); s += e[i]; }
#pragma unroll
  for (int off = 32; off >= 1; off >>= 1) s += __shfl_xor(s, off, 64);
  __syncthreads();
  if ((t & 63) == 0) red[4 + (t >> 6)] = s;
  __syncthreads();
  s = red[4] + red[5] + red[6] + red[7];
  float inv = 1.f / s;
  ushort4 o;
  o.x = f2b(e[0] * inv); o.y = f2b(e[1] * inv);
  o.z = f2b(e[2] * inv); o.w = f2b(e[3] * inv);
  ((ushort4*)(P + row * 1024))[t] = o;
}

// ---------------------------------------------------------------------------
// LayerNorm over last dim 1024 (bf16 in/out). One block per row.
// ---------------------------------------------------------------------------
DEV float block_sum(float v, float* red, int t) {
#pragma unroll
  for (int off = 32; off >= 1; off >>= 1) v += __shfl_xor(v, off, 64);
  __syncthreads();
  if ((t & 63) == 0) red[t >> 6] = v;
  __syncthreads();
  return red[0] + red[1] + red[2] + red[3];
}

__global__ __launch_bounds__(256) void layernorm_kernel(
    const unsigned short* __restrict__ X, const unsigned short* __restrict__ G,
    const unsigned short* __restrict__ Bt, unsigned short* __restrict__ Y) {
  __shared__ float red[4];
  const long row = blockIdx.x;
  const int t = threadIdx.x;
  ushort4 u = ((const ushort4*)(X + row * 1024))[t];
  float x[4] = {b2f(u.x), b2f(u.y), b2f(u.z), b2f(u.w)};
  float s = x[0] + x[1] + x[2] + x[3];
  float mean = block_sum(s, red, t) * (1.f / 1024.f);
  float d0 = x[0] - mean, d1 = x[1] - mean, d2 = x[2] - mean, d3 = x[3] - mean;
  float vs = d0 * d0 + d1 * d1 + d2 * d2 + d3 * d3;
  float var = block_sum(vs, red, t) * (1.f / 1024.f);
  float rs = rsqrtf(var + 1e-5f);
  ushort4 gu = ((const ushort4*)G)[t];
  ushort4 bu = ((const ushort4*)Bt)[t];
  ushort4 o;
  o.x = f2b(d0 * rs * b2f(gu.x) + b2f(bu.x));
  o.y = f2b(d1 * rs * b2f(gu.y) + b2f(bu.y));
  o.z = f2b(d2 * rs * b2f(gu.z) + b2f(bu.z));
  o.w = f2b(d3 * rs * b2f(gu.w) + b2f(bu.w));
  ((ushort4*)(Y + row * 1024))[t] = o;
}

// ---------------------------------------------------------------------------
// Transpose per batch: V[b][sk][d] -> VT[b][d][sk]
// ---------------------------------------------------------------------------
__global__ __launch_bounds__(256) void transpose_kernel(
    const unsigned short* __restrict__ V, unsigned short* __restrict__ VT) {
  __shared__ unsigned short tile[32][33];
  const int b = blockIdx.z;
  const int d0 = blockIdx.x * 32, sk0 = blockIdx.y * 32;
  const int tx = threadIdx.x & 31, ty = threadIdx.x >> 5;
#pragma unroll
  for (int i = 0; i < 32; i += 8)
    tile[ty + i][tx] = V[((long)(b * 1024 + sk0 + ty + i)) * 1024 + d0 + tx];
  __syncthreads();
#pragma unroll
  for (int i = 0; i < 32; i += 8)
    VT[((long)(b * 1024 + d0 + ty + i)) * 1024 + sk0 + tx] = tile[tx][ty + i];
}

// ---------------------------------------------------------------------------
// Flash MHA v2: H=16 heads, DH=64. No online max (scores bounded: LN'd q,k),
// denominator via P*ones MFMA (no cross-lane reductions). Block = 4 waves x
// 32 q-rows = 128 q-rows, one (b,h). K/V kv-tiles (32) staged in LDS, double
// buffered, one barrier per tile. K staged as two dh-halves so LDS fragment
// stride is 64B (2-way bank aliasing = free).
// ---------------------------------------------------------------------------
__global__ __launch_bounds__(256, 2) void flash_mha_kernel(
    const unsigned short* __restrict__ Q, const unsigned short* __restrict__ K,
    const unsigned short* __restrict__ VT, void* __restrict__ O,
    const int* __restrict__ flag) {
  __shared__ unsigned short sK[2][2][32 * 32];  // [buf][dh-half][kv][dh'32]
  __shared__ unsigned short sV[2][64 * 32];     // [buf][dh][kv]
  __shared__ unsigned short sP[4][32 * 32];     // [wave][m][kv]
  const int t = threadIdx.x;
  const int wave = t >> 6, lane = t & 63;
  const int quad = lane >> 4, col = lane & 15;
  const int b = blockIdx.z, h = blockIdx.y;
  const int q0 = blockIdx.x * 128 + wave * 32;

  // staging source pointers (advance by kv each tile)
  const int h2 = t >> 7, i7 = t & 127;
  const unsigned short* Ksrc =
      K + ((long)(b * 1024 + (i7 >> 2))) * 1024 + h * 64 + h2 * 32 + (i7 & 3) * 8;
  const unsigned short* Vsrc =
      VT + ((long)(b * 1024 + h * 64 + (t >> 2))) * 1024 + (t & 3) * 8;

  // Q fragments: 2 m-tiles x 2 dh-halves
  bf16x8 aq[2][2];
  {
    const unsigned short* qp =
        Q + ((long)(b * 1024 + q0 + col)) * 1024 + h * 64 + quad * 8;
    aq[0][0] = *(const bf16x8*)(qp);
    aq[0][1] = *(const bf16x8*)(qp + 32);
    aq[1][0] = *(const bf16x8*)(qp + 16 * 1024);
    aq[1][1] = *(const bf16x8*)(qp + 16 * 1024 + 32);
  }

  const f32x4 zz = {0.f, 0.f, 0.f, 0.f};
  f32x4 o[2][4], l[2];
#pragma unroll
  for (int mt = 0; mt < 2; mt++) {
    l[mt] = zz;
#pragma unroll
    for (int n = 0; n < 4; n++) o[mt][n] = zz;
  }
  bf16x8 ones;
#pragma unroll
  for (int i = 0; i < 8; i++) ones[i] = (short)0x3F80;  // bf16 1.0

#define STAGE_KV(bi, kv0)                                             \
  {                                                                   \
    GLOAD_LDS16(Ksrc + (long)(kv0) * 1024, &sK[bi][h2][i7 * 8]);      \
    GLOAD_LDS16(Vsrc + (kv0), &sV[bi][t * 8]);                        \
  }

  STAGE_KV(0, 0);
  unsigned short* pw = &sP[wave][0];
  for (int kt = 0; kt < 32; kt++) {
    const int bi = kt & 1;
    __syncthreads();  // staging of buf bi done; all waves done with buf bi
    if (kt < 31) STAGE_KV(bi ^ 1, (kt + 1) * 32);

    // QK^T
    bf16x8 kf[2][2];
#pragma unroll
    for (int nt = 0; nt < 2; nt++)
#pragma unroll
      for (int kh = 0; kh < 2; kh++)
        kf[nt][kh] = *(const bf16x8*)&sK[bi][kh][(nt * 16 + col) * 32 + quad * 8];
    f32x4 s[2][2];
#pragma unroll
    for (int mt = 0; mt < 2; mt++)
#pragma unroll
      for (int nt = 0; nt < 2; nt++) {
        s[mt][nt] = MFMA16(aq[mt][0], kf[nt][0], zz);
        s[mt][nt] = MFMA16(aq[mt][1], kf[nt][1], s[mt][nt]);
      }
    // p = exp(s/8), pack bf16 into per-wave P buffer (C-layout -> A-layout)
#pragma unroll
    for (int mt = 0; mt < 2; mt++)
#pragma unroll
      for (int nt = 0; nt < 2; nt++)
#pragma unroll
        for (int r = 0; r < 4; r++) {
          float p = __expf(s[mt][nt][r] * 0.125f);
          pw[(mt * 16 + quad * 4 + r) * 32 + nt * 16 + col] = f2b_trunc(p);
        }
    __asm__ __volatile__("s_waitcnt lgkmcnt(0)" ::: "memory");
    bf16x8 ap[2];
#pragma unroll
    for (int mt = 0; mt < 2; mt++)
      ap[mt] = *(const bf16x8*)&pw[(mt * 16 + col) * 32 + quad * 8];
    // denominator via ones-MFMA (same C-layout as o)
#pragma unroll
    for (int mt = 0; mt < 2; mt++) l[mt] = MFMA16(ap[mt], ones, l[mt]);
    // PV
    bf16x8 vf[4];
#pragma unroll
    for (int n = 0; n < 4; n++)
      vf[n] = *(const bf16x8*)&sV[bi][(n * 16 + col) * 32 + quad * 8];
#pragma unroll
    for (int mt = 0; mt < 2; mt++)
#pragma unroll
      for (int n = 0; n < 4; n++) o[mt][n] = MFMA16(ap[mt], vf[n], o[mt][n]);
  }
#undef STAGE_KV

  const int f32o = *flag;
#pragma unroll
  for (int mt = 0; mt < 2; mt++)
#pragma unroll
    for (int r = 0; r < 4; r++) {
      float inv = 1.f / l[mt][r];
      const long base =
          ((long)(b * 1024 + q0 + mt * 16 + quad * 4 + r)) * 1024 + h * 64 + col;
      if (f32o) {
        float* Of = (float*)O;
#pragma unroll
        for (int n = 0; n < 4; n++) Of[base + n * 16] = o[mt][n][r] * inv;
      } else {
        unsigned short* Ou = (unsigned short*)O;
#pragma unroll
        for (int n = 0; n < 4; n++) Ou[base + n * 16] = f2b(o[mt][n][r] * inv);
      }
    }
}

// ---------------------------------------------------------------------------
extern "C" void kernel_launch(void* const* d_in, const int* in_sizes, int n_in,
                              void* d_out, int out_size, void* d_ws,
                              size_t ws_size, hipStream_t stream) {
  (void)in_sizes; (void)n_in; (void)out_size; (void)ws_size;
  const void* hs   = d_in[0];
  const void* ctx  = d_in[1];
  const void* Wq   = d_in[2];
  const void* bq   = d_in[3];
  const void* Wk   = d_in[4];
  const void* bk   = d_in[5];
  const void* Wv   = d_in[6];
  const void* bv   = d_in[7];
  const void* Wobs = d_in[8];
  const void* bobs = d_in[9];
  const void* Wmat = d_in[10];
  const void* bmat = d_in[11];
  const void* lng  = d_in[12];
  const void* lnb  = d_in[13];

  const long E = 8LL * 1024 * 1024;
  const long W1 = 1024L * 1024L;
  unsigned short* base = (unsigned short*)d_ws;
  unsigned short* hsb   = base;                  // later: probs
  unsigned short* ctxb  = base + E;              // later: gctx
  unsigned short* Wb    = base + 2 * E;          // 5 x 1M
  unsigned short* Wqb   = Wb;
  unsigned short* Wkb   = Wb + W1;
  unsigned short* Wvb   = Wb + 2 * W1;
  unsigned short* Wobsb = Wb + 3 * W1;
  unsigned short* Wmatb = Wb + 4 * W1;
  unsigned short* vecs  = base + 2 * E + 5 * W1;
  unsigned short* bqb   = vecs;
  unsigned short* bkb   = vecs + 1024;
  unsigned short* bvb   = vecs + 2048;
  unsigned short* bobsb = vecs + 3072;
  unsigned short* bmatb = vecs + 4096;
  unsigned short* lngb  = vecs + 5120;
  unsigned short* lnbb  = vecs + 6144;
  int* flag = (int*)(vecs + 32768);
  unsigned short* q     = vecs + W1;             // later: newk
  unsigned short* k     = q + E;
  unsigned short* v     = k + E;                 // later: nk
  unsigned short* vT    = v + E;
  float* scores = (float*)(vT + E);
  unsigned short* nq    = (unsigned short*)scores;
  unsigned short* newq  = ((unsigned short*)scores) + E;
  unsigned short* probs = hsb;
  unsigned short* gctx  = ctxb;
  unsigned short* nk    = v;
  unsigned short* newk  = q;

  dim3 blk(256);
  const long S1 = 1024L * 1024L;

  detect_kernel<<<dim3(1), blk, 0, stream>>>((const unsigned short*)hs, flag);
  convert_kernel<<<dim3(8192), blk, 0, stream>>>(hs, hsb, (int)E, flag);
  convert_kernel<<<dim3(8192), blk, 0, stream>>>(ctx, ctxb, (int)E, flag);
  convert_w_kernel<<<dim3(1024, 5), blk, 0, stream>>>(Wq, Wk, Wv, Wobs, Wmat, Wb, flag);
  convert_vec_kernel<<<dim3(7), blk, 0, stream>>>(bq, bk, bv, bobs, bmat, lng, lnb,
                                                  vecs, flag);

  gemm_bt_kernel<0, 1, 1><<<dim3(64, 8, 1), blk, 0, stream>>>(
      hsb, Wqb, bqb, q, 8192, 1024, 1024, 0, 0, 0, 1.f);
  gemm_bt_kernel<0, 1, 1><<<dim3(64, 8, 1), blk, 0, stream>>>(
      ctxb, Wkb, bkb, k, 8192, 1024, 1024, 0, 0, 0, 1.f);
  gemm_bt_kernel<0, 1, 1><<<dim3(64, 8, 1), blk, 0, stream>>>(
      ctxb, Wvb, bvb, v, 8192, 1024, 1024, 0, 0, 0, 1.f);
  transpose_kernel<<<dim3(32, 32, 8), blk, 0, stream>>>(v, vT);
  gemm_bt_kernel<0, 0, 0><<<dim3(8, 8, 8), blk, 0, stream>>>(
      q, k, nullptr, scores, 1024, 1024, 1024, S1, S1, S1, 0.03125f);
  softmax_kernel<<<dim3(8192), blk, 0, stream>>>(scores, probs);
  gemm_bt_kernel<0, 1, 0><<<dim3(8, 8, 8), blk, 0, stream>>>(
      probs, vT, nullptr, gctx, 1024, 1024, 1024, S1, S1, S1, 1.f);
  gemm_bt_kernel<1, 1, 1><<<dim3(64, 8, 1), blk, 0, stream>>>(
      gctx, Wobsb, bobsb, nq, 8192, 1024, 1024, 0, 0, 0, 1.f);
  gemm_bt_kernel<1, 1, 1><<<dim3(64, 8, 1), blk, 0, stream>>>(
      k, Wmatb, bmatb, nk, 8192, 1024, 1024, 0, 0, 0, 1.f);
  layernorm_kernel<<<dim3(8192), blk, 0, stream>>>(nq, lngb, lnbb, newq);
  layernorm_kernel<<<dim3(8192), blk, 0, stream>>>(nk, lngb, lnbb, newk);
  flash_mha_kernel<<<dim3(8, 16, 8), blk, 0, stream>>>(
      newq, newk, vT, d_out, flag);
}

// Round 4
// 405.376 us; speedup vs baseline: 1.7813x; 1.3585x over previous
//
#include <hip/hip_runtime.h>
#include <hip/hip_bf16.h>

#define DEV __device__ __forceinline__

using bf16x8 = __attribute__((ext_vector_type(8))) short;   // 8 bf16 in 4 VGPRs
using f32x4  = __attribute__((ext_vector_type(4))) float;

#define MFMA16(a, b, c) __builtin_amdgcn_mfma_f32_16x16x32_bf16((a), (b), (c), 0, 0, 0)

// async global->LDS, 16 bytes per lane. LDS dst must be wave-uniform base + lane*16.
#define GLOAD_LDS16(gp, lp)                                                        \
  __builtin_amdgcn_global_load_lds(                                               \
      (__attribute__((address_space(1))) unsigned int*)(gp),                      \
      (__attribute__((address_space(3))) unsigned int*)(lp), 16, 0, 0)

DEV float b2f(unsigned short u) {
  union { float f; unsigned u; } x; x.u = ((unsigned)u) << 16; return x.f;
}
DEV unsigned short f2b(float f) {   // round-to-nearest-even bf16
  union { float f; unsigned u; } x; x.f = f;
  unsigned r = x.u + 0x7FFFu + ((x.u >> 16) & 1u);
  return (unsigned short)(r >> 16);
}
DEV unsigned short f2b_trunc(float f) {  // truncate: bias cancels (l from same P)
  union { float f; unsigned u; } x; x.f = f;
  return (unsigned short)(x.u >> 16);
}

// ---------------------------------------------------------------------------
// Dtype detector v2: fp32 data read as u16 halves shows bf16 NaN/Inf exponent
// patterns (~1/256 of low halves); true bf16 gaussian data shows none.
// 16K u16 sample (mean ~32 hits for fp32), coalesced ushort4 loads, ~2us.
// ---------------------------------------------------------------------------
__global__ __launch_bounds__(256) void detect_kernel(
    const unsigned short* __restrict__ hs, int* __restrict__ flag) {
  __shared__ int red[4];
  const int t = threadIdx.x;
  const ushort4* p = (const ushort4*)hs;
  int cnt = 0;
#pragma unroll
  for (int j = 0; j < 16; j++) {
    ushort4 u = p[j * 256 + t];
    cnt += (((u.x >> 7) & 0xFF) == 0xFF) + (((u.y >> 7) & 0xFF) == 0xFF) +
           (((u.z >> 7) & 0xFF) == 0xFF) + (((u.w >> 7) & 0xFF) == 0xFF);
  }
#pragma unroll
  for (int off = 32; off >= 1; off >>= 1) cnt += __shfl_xor(cnt, off, 64);
  if ((t & 63) == 0) red[t >> 6] = cnt;
  __syncthreads();
  if (t == 0) flag[0] = (red[0] + red[1] + red[2] + red[3] >= 4) ? 1 : 0;
}

// Convert hs+ctx in one launch: 16384 blocks, block handles 1024 elems.
__global__ __launch_bounds__(256) void convert2_kernel(
    const void* __restrict__ s0, const void* __restrict__ s1,
    unsigned short* __restrict__ d0, unsigned short* __restrict__ d1,
    const int* __restrict__ flag) {
  const int bid = blockIdx.x;
  const void* src;
  unsigned short* dst;
  long off;
  if (bid < 8192) { src = s0; dst = d0; off = (long)bid * 1024; }
  else            { src = s1; dst = d1; off = (long)(bid - 8192) * 1024; }
  const long i = off + threadIdx.x * 4;
  ushort4 o;
  if (*flag) {
    float4 f = ((const float4*)src)[i >> 2];
    o.x = f2b(f.x); o.y = f2b(f.y); o.z = f2b(f.z); o.w = f2b(f.w);
  } else {
    o = ((const ushort4*)src)[i >> 2];
  }
  ((ushort4*)dst)[i >> 2] = o;
}

__global__ __launch_bounds__(256) void convert_w_kernel(
    const void* __restrict__ s0, const void* __restrict__ s1,
    const void* __restrict__ s2, const void* __restrict__ s3,
    const void* __restrict__ s4, unsigned short* __restrict__ dst,
    const int* __restrict__ flag) {
  const void* srcs[5] = {s0, s1, s2, s3, s4};
  const void* src = srcs[blockIdx.y];
  unsigned short* d = dst + (long)blockIdx.y * 1048576;
  const int i = (blockIdx.x * 256 + threadIdx.x) * 4;
  ushort4 o;
  if (*flag) {
    float4 f = ((const float4*)src)[i >> 2];
    o.x = f2b(f.x); o.y = f2b(f.y); o.z = f2b(f.z); o.w = f2b(f.w);
  } else {
    o = ((const ushort4*)src)[i >> 2];
  }
  ((ushort4*)d)[i >> 2] = o;
}

__global__ __launch_bounds__(256) void convert_vec_kernel(
    const void* __restrict__ s0, const void* __restrict__ s1,
    const void* __restrict__ s2, const void* __restrict__ s3,
    const void* __restrict__ s4, const void* __restrict__ s5,
    const void* __restrict__ s6, unsigned short* __restrict__ dst,
    const int* __restrict__ flag) {
  const void* srcs[7] = {s0, s1, s2, s3, s4, s5, s6};
  const void* src = srcs[blockIdx.x];
  unsigned short* d = dst + blockIdx.x * 1024;
  const int i = threadIdx.x * 4;
  ushort4 o;
  if (*flag) {
    float4 f = ((const float4*)src)[i >> 2];
    o.x = f2b(f.x); o.y = f2b(f.y); o.z = f2b(f.z); o.w = f2b(f.w);
  } else {
    o = ((const ushort4*)src)[i >> 2];
  }
  ((ushort4*)d)[i >> 2] = o;
}

// ---------------------------------------------------------------------------
// GEMM: C[m,n] = scale * sum_k A[m,k]*B[n,k] + bias[n]  (B row-major [N,K])
// Tile 128x128, BK=64 as two 32-wide k-panels (keeps LDS fragment stride 64B,
// same bank profile as BK=32, half the barriers). 4 waves 2x2, wave 64x64.
// SPLIT: N=2048 fused k|v projection; blocks y>=8 write Cv2 with stride N/2.
// ---------------------------------------------------------------------------
template <int RELU, int OUTBF16, int BIAS, int SPLIT>
__global__ __launch_bounds__(256, 2) void gemm_bt_kernel(
    const unsigned short* __restrict__ A, const unsigned short* __restrict__ B,
    const unsigned short* __restrict__ bias, void* __restrict__ Cv,
    void* __restrict__ Cv2, int M, int N, int K, long sA_, long sB_, long sC_,
    float scale) {
  __shared__ unsigned short sA[2][128 * 32];   // [k-panel][row][32]
  __shared__ unsigned short sB[2][128 * 32];
  const int t = threadIdx.x;
  const int wave = t >> 6, lane = t & 63;
  const int quad = lane >> 4, col = lane & 15;
  const int wm = wave >> 1, wn = wave & 1;
  const long zb = blockIdx.z;
  const unsigned short* Ab = A + zb * sA_ + (long)blockIdx.x * 128 * K;
  const unsigned short* Bb = B + zb * sB_ + (long)blockIdx.y * 128 * K;
  const int r0 = t >> 2;          // 0..63
  const int c0 = (t & 3) * 8;     // 0,8,16,24

  f32x4 zz = {0.f, 0.f, 0.f, 0.f};
  f32x4 acc[4][4];
#pragma unroll
  for (int i = 0; i < 4; i++)
#pragma unroll
    for (int j = 0; j < 4; j++) acc[i][j] = zz;

  for (int k0 = 0; k0 < K; k0 += 64) {
    __syncthreads();
#pragma unroll
    for (int p = 0; p < 2; p++) {
      GLOAD_LDS16(Ab + (long)r0 * K + k0 + p * 32 + c0,        &sA[p][t * 8]);
      GLOAD_LDS16(Ab + (long)(64 + r0) * K + k0 + p * 32 + c0, &sA[p][2048 + t * 8]);
      GLOAD_LDS16(Bb + (long)r0 * K + k0 + p * 32 + c0,        &sB[p][t * 8]);
      GLOAD_LDS16(Bb + (long)(64 + r0) * K + k0 + p * 32 + c0, &sB[p][2048 + t * 8]);
    }
    __syncthreads();
#pragma unroll
    for (int p = 0; p < 2; p++) {
      bf16x8 af[4], bfr[4];
#pragma unroll
      for (int mi = 0; mi < 4; mi++)
        af[mi] = *(const bf16x8*)&sA[p][(wm * 64 + mi * 16 + col) * 32 + quad * 8];
#pragma unroll
      for (int ni = 0; ni < 4; ni++)
        bfr[ni] = *(const bf16x8*)&sB[p][(wn * 64 + ni * 16 + col) * 32 + quad * 8];
#pragma unroll
      for (int mi = 0; mi < 4; mi++)
#pragma unroll
        for (int ni = 0; ni < 4; ni++)
          acc[mi][ni] = MFMA16(af[mi], bfr[ni], acc[mi][ni]);
    }
  }

  const int Rm = blockIdx.x * 128 + wm * 64;
  const int Cn = blockIdx.y * 128 + wn * 64;
  float bs[4];
#pragma unroll
  for (int ni = 0; ni < 4; ni++)
    bs[ni] = BIAS ? b2f(bias[Cn + ni * 16 + col]) : 0.f;

  unsigned short* Cb = (unsigned short*)Cv;
  int Nw = N, cadj = 0;
  if (SPLIT) {
    Nw = N >> 1;
    if (blockIdx.y >= (gridDim.y >> 1)) { Cb = (unsigned short*)Cv2; cadj = Nw; }
  }
#pragma unroll
  for (int mi = 0; mi < 4; mi++)
#pragma unroll
    for (int ni = 0; ni < 4; ni++)
#pragma unroll
      for (int r = 0; r < 4; r++) {
        int rr = Rm + mi * 16 + quad * 4 + r;
        int cc = Cn + ni * 16 + col;
        float v = acc[mi][ni][r] * scale + bs[ni];
        if (RELU) v = fmaxf(v, 0.f);
        if (OUTBF16)
          Cb[zb * sC_ + (long)rr * Nw + (cc - cadj)] = f2b(v);
        else
          ((float*)Cv)[zb * sC_ + (long)rr * N + cc] = v;
      }
}

// ---------------------------------------------------------------------------
// Row softmax: S fp32 [rows,1024] -> P bf16. One block per row.
// ---------------------------------------------------------------------------
__global__ __launch_bounds__(256) void softmax_kernel(
    const float* __restrict__ S, unsigned short* __restrict__ P) {
  __shared__ float red[8];
  const long row = blockIdx.x;
  const int t = threadIdx.x;
  const float4 v4 = ((const float4*)(S + row * 1024))[t];
  float x[4] = {v4.x, v4.y, v4.z, v4.w};
  float m = fmaxf(fmaxf(x[0], x[1]), fmaxf(x[2], x[3]));
#pragma unroll
  for (int off = 32; off >= 1; off >>= 1) m = fmaxf(m, __shfl_xor(m, off, 64));
  if ((t & 63) == 0) red[t >> 6] = m;
  __syncthreads();
  m = fmaxf(fmaxf(red[0], red[1]), fmaxf(red[2], red[3]));
  float e[4], s = 0.f;
#pragma unroll
  for (int i = 0; i < 4; i++) { e[i] = __expf(x[i] - m); s += e[i]; }
#pragma unroll
  for (int off = 32; off >= 1; off >>= 1) s += __shfl_xor(s, off, 64);
  __syncthreads();
  if ((t & 63) == 0) red[4 + (t >> 6)] = s;
  __syncthreads();
  s = red[4] + red[5] + red[6] + red[7];
  float inv = 1.f / s;
  ushort4 o;
  o.x = f2b(e[0] * inv); o.y = f2b(e[1] * inv);
  o.z = f2b(e[2] * inv); o.w = f2b(e[3] * inv);
  ((ushort4*)(P + row * 1024))[t] = o;
}

// ---------------------------------------------------------------------------
// LayerNorm over last dim 1024, two tensors in one launch (16384 blocks).
// ---------------------------------------------------------------------------
DEV float block_sum(float v, float* red, int t) {
#pragma unroll
  for (int off = 32; off >= 1; off >>= 1) v += __shfl_xor(v, off, 64);
  __syncthreads();
  if ((t & 63) == 0) red[t >> 6] = v;
  __syncthreads();
  return red[0] + red[1] + red[2] + red[3];
}

__global__ __launch_bounds__(256) void layernorm2_kernel(
    const unsigned short* __restrict__ X0, const unsigned short* __restrict__ X1,
    const unsigned short* __restrict__ G, const unsigned short* __restrict__ Bt,
    unsigned short* __restrict__ Y0, unsigned short* __restrict__ Y1) {
  __shared__ float red[4];
  const int bid = blockIdx.x;
  const unsigned short* X;
  unsigned short* Y;
  if (bid < 8192) { X = X0 + (long)bid * 1024; Y = Y0 + (long)bid * 1024; }
  else { X = X1 + (long)(bid - 8192) * 1024; Y = Y1 + (long)(bid - 8192) * 1024; }
  const int t = threadIdx.x;
  ushort4 u = ((const ushort4*)X)[t];
  float x[4] = {b2f(u.x), b2f(u.y), b2f(u.z), b2f(u.w)};
  float s = x[0] + x[1] + x[2] + x[3];
  float mean = block_sum(s, red, t) * (1.f / 1024.f);
  float d0 = x[0] - mean, d1 = x[1] - mean, d2 = x[2] - mean, d3 = x[3] - mean;
  float vs = d0 * d0 + d1 * d1 + d2 * d2 + d3 * d3;
  float var = block_sum(vs, red, t) * (1.f / 1024.f);
  float rs = rsqrtf(var + 1e-5f);
  ushort4 gu = ((const ushort4*)G)[t];
  ushort4 bu = ((const ushort4*)Bt)[t];
  ushort4 o;
  o.x = f2b(d0 * rs * b2f(gu.x) + b2f(bu.x));
  o.y = f2b(d1 * rs * b2f(gu.y) + b2f(bu.y));
  o.z = f2b(d2 * rs * b2f(gu.z) + b2f(bu.z));
  o.w = f2b(d3 * rs * b2f(gu.w) + b2f(bu.w));
  ((ushort4*)Y)[t] = o;
}

// ---------------------------------------------------------------------------
// Transpose per batch: V[b][sk][d] -> VT[b][d][sk]
// ---------------------------------------------------------------------------
__global__ __launch_bounds__(256) void transpose_kernel(
    const unsigned short* __restrict__ V, unsigned short* __restrict__ VT) {
  __shared__ unsigned short tile[32][33];
  const int b = blockIdx.z;
  const int d0 = blockIdx.x * 32, sk0 = blockIdx.y * 32;
  const int tx = threadIdx.x & 31, ty = threadIdx.x >> 5;
#pragma unroll
  for (int i = 0; i < 32; i += 8)
    tile[ty + i][tx] = V[((long)(b * 1024 + sk0 + ty + i)) * 1024 + d0 + tx];
  __syncthreads();
#pragma unroll
  for (int i = 0; i < 32; i += 8)
    VT[((long)(b * 1024 + d0 + ty + i)) * 1024 + sk0 + tx] = tile[tx][ty + i];
}

// ---------------------------------------------------------------------------
// Flash MHA v2: H=16 heads, DH=64. No online max (scores bounded: LN'd q,k),
// denominator via P*ones MFMA. Block = 4 waves x 32 q-rows, one (b,h).
// K/V kv-tiles (32) in LDS, double buffered, one barrier per tile.
// ---------------------------------------------------------------------------
__global__ __launch_bounds__(256, 2) void flash_mha_kernel(
    const unsigned short* __restrict__ Q, const unsigned short* __restrict__ K,
    const unsigned short* __restrict__ VT, void* __restrict__ O,
    const int* __restrict__ flag) {
  __shared__ unsigned short sK[2][2][32 * 32];  // [buf][dh-half][kv][dh'32]
  __shared__ unsigned short sV[2][64 * 32];     // [buf][dh][kv]
  __shared__ unsigned short sP[4][32 * 32];     // [wave][m][kv]
  const int t = threadIdx.x;
  const int wave = t >> 6, lane = t & 63;
  const int quad = lane >> 4, col = lane & 15;
  const int b = blockIdx.z, h = blockIdx.y;
  const int q0 = blockIdx.x * 128 + wave * 32;

  const int h2 = t >> 7, i7 = t & 127;
  const unsigned short* Ksrc =
      K + ((long)(b * 1024 + (i7 >> 2))) * 1024 + h * 64 + h2 * 32 + (i7 & 3) * 8;
  const unsigned short* Vsrc =
      VT + ((long)(b * 1024 + h * 64 + (t >> 2))) * 1024 + (t & 3) * 8;

  bf16x8 aq[2][2];
  {
    const unsigned short* qp =
        Q + ((long)(b * 1024 + q0 + col)) * 1024 + h * 64 + quad * 8;
    aq[0][0] = *(const bf16x8*)(qp);
    aq[0][1] = *(const bf16x8*)(qp + 32);
    aq[1][0] = *(const bf16x8*)(qp + 16 * 1024);
    aq[1][1] = *(const bf16x8*)(qp + 16 * 1024 + 32);
  }

  const f32x4 zz = {0.f, 0.f, 0.f, 0.f};
  f32x4 o[2][4], l[2];
#pragma unroll
  for (int mt = 0; mt < 2; mt++) {
    l[mt] = zz;
#pragma unroll
    for (int n = 0; n < 4; n++) o[mt][n] = zz;
  }
  bf16x8 ones;
#pragma unroll
  for (int i = 0; i < 8; i++) ones[i] = (short)0x3F80;  // bf16 1.0

#define STAGE_KV(bi, kv0)                                             \
  {                                                                   \
    GLOAD_LDS16(Ksrc + (long)(kv0) * 1024, &sK[bi][h2][i7 * 8]);      \
    GLOAD_LDS16(Vsrc + (kv0), &sV[bi][t * 8]);                        \
  }

  STAGE_KV(0, 0);
  unsigned short* pw = &sP[wave][0];
  for (int kt = 0; kt < 32; kt++) {
    const int bi = kt & 1;
    __syncthreads();
    if (kt < 31) STAGE_KV(bi ^ 1, (kt + 1) * 32);

    bf16x8 kf[2][2];
#pragma unroll
    for (int nt = 0; nt < 2; nt++)
#pragma unroll
      for (int kh = 0; kh < 2; kh++)
        kf[nt][kh] = *(const bf16x8*)&sK[bi][kh][(nt * 16 + col) * 32 + quad * 8];
    f32x4 s[2][2];
#pragma unroll
    for (int mt = 0; mt < 2; mt++)
#pragma unroll
      for (int nt = 0; nt < 2; nt++) {
        s[mt][nt] = MFMA16(aq[mt][0], kf[nt][0], zz);
        s[mt][nt] = MFMA16(aq[mt][1], kf[nt][1], s[mt][nt]);
      }
#pragma unroll
    for (int mt = 0; mt < 2; mt++)
#pragma unroll
      for (int nt = 0; nt < 2; nt++)
#pragma unroll
        for (int r = 0; r < 4; r++) {
          float p = __expf(s[mt][nt][r] * 0.125f);
          pw[(mt * 16 + quad * 4 + r) * 32 + nt * 16 + col] = f2b_trunc(p);
        }
    __asm__ __volatile__("s_waitcnt lgkmcnt(0)" ::: "memory");
    bf16x8 ap[2];
#pragma unroll
    for (int mt = 0; mt < 2; mt++)
      ap[mt] = *(const bf16x8*)&pw[(mt * 16 + col) * 32 + quad * 8];
#pragma unroll
    for (int mt = 0; mt < 2; mt++) l[mt] = MFMA16(ap[mt], ones, l[mt]);
    bf16x8 vf[4];
#pragma unroll
    for (int n = 0; n < 4; n++)
      vf[n] = *(const bf16x8*)&sV[bi][(n * 16 + col) * 32 + quad * 8];
#pragma unroll
    for (int mt = 0; mt < 2; mt++)
#pragma unroll
      for (int n = 0; n < 4; n++) o[mt][n] = MFMA16(ap[mt], vf[n], o[mt][n]);
  }
#undef STAGE_KV

  const int f32o = *flag;
#pragma unroll
  for (int mt = 0; mt < 2; mt++)
#pragma unroll
    for (int r = 0; r < 4; r++) {
      float inv = 1.f / l[mt][r];
      const long base =
          ((long)(b * 1024 + q0 + mt * 16 + quad * 4 + r)) * 1024 + h * 64 + col;
      if (f32o) {
        float* Of = (float*)O;
#pragma unroll
        for (int n = 0; n < 4; n++) Of[base + n * 16] = o[mt][n][r] * inv;
      } else {
        unsigned short* Ou = (unsigned short*)O;
#pragma unroll
        for (int n = 0; n < 4; n++) Ou[base + n * 16] = f2b(o[mt][n][r] * inv);
      }
    }
}

// ---------------------------------------------------------------------------
extern "C" void kernel_launch(void* const* d_in, const int* in_sizes, int n_in,
                              void* d_out, int out_size, void* d_ws,
                              size_t ws_size, hipStream_t stream) {
  (void)in_sizes; (void)n_in; (void)out_size; (void)ws_size;
  const void* hs   = d_in[0];
  const void* ctx  = d_in[1];
  const void* Wq   = d_in[2];
  const void* bq   = d_in[3];
  const void* Wk   = d_in[4];
  const void* bk   = d_in[5];
  const void* Wv   = d_in[6];
  const void* bv   = d_in[7];
  const void* Wobs = d_in[8];
  const void* bobs = d_in[9];
  const void* Wmat = d_in[10];
  const void* bmat = d_in[11];
  const void* lng  = d_in[12];
  const void* lnb  = d_in[13];

  const long E = 8LL * 1024 * 1024;
  const long W1 = 1024L * 1024L;
  unsigned short* base = (unsigned short*)d_ws;
  unsigned short* hsb   = base;                  // later: probs
  unsigned short* ctxb  = base + E;              // later: gctx
  unsigned short* Wb    = base + 2 * E;          // 5 x 1M
  unsigned short* Wqb   = Wb;
  unsigned short* Wkb   = Wb + W1;               // Wk|Wv contiguous for SPLIT
  unsigned short* Wvb   = Wb + 2 * W1;
  unsigned short* Wobsb = Wb + 3 * W1;
  unsigned short* Wmatb = Wb + 4 * W1;
  unsigned short* vecs  = base + 2 * E + 5 * W1;
  unsigned short* bqb   = vecs;
  unsigned short* bkb   = vecs + 1024;           // bk|bv contiguous for SPLIT
  unsigned short* bvb   = vecs + 2048;
  unsigned short* bobsb = vecs + 3072;
  unsigned short* bmatb = vecs + 4096;
  unsigned short* lngb  = vecs + 5120;
  unsigned short* lnbb  = vecs + 6144;
  int* flag = (int*)(vecs + 32768);
  unsigned short* q     = vecs + W1;             // later: newk
  unsigned short* k     = q + E;
  unsigned short* v     = k + E;                 // later: nk
  unsigned short* vT    = v + E;
  float* scores = (float*)(vT + E);
  unsigned short* nq    = (unsigned short*)scores;
  unsigned short* newq  = ((unsigned short*)scores) + E;
  unsigned short* probs = hsb;
  unsigned short* gctx  = ctxb;
  unsigned short* nk    = v;
  unsigned short* newk  = q;

  dim3 blk(256);
  const long S1 = 1024L * 1024L;

  detect_kernel<<<dim3(1), blk, 0, stream>>>((const unsigned short*)hs, flag);
  convert2_kernel<<<dim3(16384), blk, 0, stream>>>(hs, ctx, hsb, ctxb, flag);
  convert_w_kernel<<<dim3(1024, 5), blk, 0, stream>>>(Wq, Wk, Wv, Wobs, Wmat, Wb, flag);
  convert_vec_kernel<<<dim3(7), blk, 0, stream>>>(bq, bk, bv, bobs, bmat, lng, lnb,
                                                  vecs, flag);

  // q projection
  gemm_bt_kernel<0, 1, 1, 0><<<dim3(64, 8, 1), blk, 0, stream>>>(
      hsb, Wqb, bqb, q, q, 8192, 1024, 1024, 0, 0, 0, 1.f);
  // fused k|v projection (SPLIT): B = [Wk;Wv] 2048x1024, bias = [bk;bv]
  gemm_bt_kernel<0, 1, 1, 1><<<dim3(64, 16, 1), blk, 0, stream>>>(
      ctxb, Wkb, bkb, k, v, 8192, 2048, 1024, 0, 0, 0, 1.f);
  transpose_kernel<<<dim3(32, 32, 8), blk, 0, stream>>>(v, vT);
  // scores[b] = q[b] @ k[b]^T / 32  (fp32)
  gemm_bt_kernel<0, 0, 0, 0><<<dim3(8, 8, 8), blk, 0, stream>>>(
      q, k, nullptr, scores, scores, 1024, 1024, 1024, S1, S1, S1, 0.03125f);
  softmax_kernel<<<dim3(8192), blk, 0, stream>>>(scores, probs);
  // gctx[b] = probs[b] @ v[b]  (as probs @ vT^T)
  gemm_bt_kernel<0, 1, 0, 0><<<dim3(8, 8, 8), blk, 0, stream>>>(
      probs, vT, nullptr, gctx, gctx, 1024, 1024, 1024, S1, S1, S1, 1.f);
  // nq = relu(gctx @ Wobs^T + bobs); nk = relu(k @ Wmat^T + bmat)
  gemm_bt_kernel<1, 1, 1, 0><<<dim3(64, 8, 1), blk, 0, stream>>>(
      gctx, Wobsb, bobsb, nq, nq, 8192, 1024, 1024, 0, 0, 0, 1.f);
  gemm_bt_kernel<1, 1, 1, 0><<<dim3(64, 8, 1), blk, 0, stream>>>(
      k, Wmatb, bmatb, nk, nk, 8192, 1024, 1024, 0, 0, 0, 1.f);
  // LayerNorms (merged)
  layernorm2_kernel<<<dim3(16384), blk, 0, stream>>>(nq, nk, lngb, lnbb, newq, newk);
  flash_mha_kernel<<<dim3(8, 16, 8), blk, 0, stream>>>(
      newq, newk, vT, d_out, flag);
}